// Round 13
// baseline (1345.707 us; speedup 1.0000x reference)
//
#include <hip/hip_runtime.h>
#include <hip/hip_fp8.h>
#include <math.h>

typedef __attribute__((ext_vector_type(8))) short short8v;  // 8 bf16
typedef __attribute__((ext_vector_type(4))) float f32x4;
typedef __attribute__((ext_vector_type(2))) long long i64x2;  // one 16B frag-pair
typedef unsigned long long u64;
typedef unsigned short ushort_t;
typedef unsigned char u8;

constexpr int Bb = 4;
constexpr int Ll = 512;
constexpr int Dk = 2048;
constexpr int Vv = 32000;
constexpr int Tt = 1024;
constexpr int Mrows = Bb * Ll;  // 2048

// main GEMM: 256x256 block-tile, 8 waves (2x4), wave-tile 128x64, fp8 e4m3,
// BK=64 per t-step (two K=32 chunks per 16B frag-pair), fragment-direct
// global->VGPR streaming, NO LDS / NO barriers in the main loop (R5 structure).
constexpr int BM = 256;
constexpr int BN = 256;
constexpr int NKT = 32;          // K-tiles of 64
constexpr int NBX = Mrows / BM;  // 8
constexpr int NBY = Vv / BN;     // 125
constexpr int NWG = NBX * NBY;   // 1000 (divisible by 8)
constexpr int CHUNK = NWG / 8;   // 125
// tiled operand granule: rowgrp (16 rows) x K-tile(64) = 1024 B; per (blk,t):
// 16 granules = 16 KB. lane l holds 16 B at granule + l*16: c0 frag in bytes
// 0..7 (k = t*64 + 0*32 + ((l>>4)&3)*8 + j, row = rg*16 + (l&15)), c1 in 8..15.
constexpr int TSTRIDE = 16 * 1024;  // bytes per (blk, t)

constexpr int KCAND = 8;          // rescored candidates per row
constexpr int CAND_STRIDE = 500;  // u64 per row; main path uses first 250

// fallback geometry (small-ws path, 128x128 reg-staged bf16)
constexpr int FBM = 128;
constexpr int FBN = 128;
constexpr int FNVB = Vv / FBN;  // 250

// ---- workspace layout (bytes) ----
// winv : f32[32000]         @ 0          (131072 B slot)
// best : u64[2048]          @ 131072     (16384 B)
// sel  : i32[2048*8]        @ 147456     (65536 B)
// cand : u64[2048*500]      @ 262144     (8192000 B)
// At   : fp8 tiled A        @ 8454144    (4194304 B)   [bx8][t32][rg16][1024]
// Wt   : fp8 tiled W        @ 16842752   (65536000 B)  [by125][t32][rg16][1024]
constexpr size_t WS_NEEDED = 16842752ull + 65536000ull;  // 82378752

__device__ __forceinline__ unsigned int fkey(float f) {
    unsigned int u = __float_as_uint(f);
    return (u & 0x80000000u) ? ~u : (u | 0x80000000u);
}
__device__ __forceinline__ void top2(u64& b1, u64& b2, u64 p) {
    if (p > b1) { b2 = b1; b1 = p; }
    else if (p > b2) { b2 = p; }
}
__device__ __forceinline__ u64 shfl64(u64 x, int m) {
    unsigned lo = __shfl_xor((unsigned)x, m, 64);
    unsigned hi = __shfl_xor((unsigned)(x >> 32), m, 64);
    return ((u64)hi << 32) | lo;
}
__device__ __forceinline__ u8 to_e4m3(float x) {
    __hip_fp8_e4m3 q(x);  // OCP e4m3fn, RNE+sat
    return q.__x;
}

// ---- convert A: f32 -> fp8 e4m3, tiled in 1KB fragment-granules ----
// element (row,k): bx=row>>8, rg=(row&255)>>4, r15=row&15; t=k>>6, c=(k>>5)&1,
// lane' = r15 + ((k>>3)&3)*16, byte j=k&7.
// dst = ((bx*NKT + t)*16 + rg)*1024 + lane'*16 + c*8 + j.
__global__ __launch_bounds__(256) void convertA_fp8(const float* __restrict__ A,
                                                    u8* __restrict__ At) {
    const int row = blockIdx.x * 4 + (threadIdx.x >> 6);
    const int lane = threadIdx.x & 63;
    const int bx = row >> 8, rg = (row & 255) >> 4, r15 = row & 15;
    const float* src = A + (size_t)row * Dk;
#pragma unroll
    for (int i = 0; i < 4; ++i) {
        const int k0 = (i * 64 + lane) * 8;
        float4 x = *(const float4*)(src + k0);
        float4 y = *(const float4*)(src + k0 + 4);
        u8 o[8] = {to_e4m3(x.x), to_e4m3(x.y), to_e4m3(x.z), to_e4m3(x.w),
                   to_e4m3(y.x), to_e4m3(y.y), to_e4m3(y.z), to_e4m3(y.w)};
        const int t = k0 >> 6, c = (k0 >> 5) & 1, lp = r15 + ((k0 >> 3) & 3) * 16;
        *(u64*)(At + ((size_t)(bx * NKT + t) * 16 + rg) * 1024 + lp * 16 + c * 8) =
            *(const u64*)o;
    }
}

// ---- convert W: f32 -> fp8 e4m3 (x64 uniform scale), tiled + fused winv ----
__global__ __launch_bounds__(256) void convertW_fp8(const float* __restrict__ W,
                                                    u8* __restrict__ Wt,
                                                    float* __restrict__ winv) {
    const int row = blockIdx.x * 4 + (threadIdx.x >> 6);
    const int lane = threadIdx.x & 63;
    const int by = row >> 8, rg = (row & 255) >> 4, r15 = row & 15;
    const float* src = W + (size_t)row * Dk;
    float sq = 0.f;
#pragma unroll
    for (int i = 0; i < 4; ++i) {
        const int k0 = (i * 64 + lane) * 8;
        float4 x = *(const float4*)(src + k0);
        float4 y = *(const float4*)(src + k0 + 4);
        sq = fmaf(x.x, x.x, sq); sq = fmaf(x.y, x.y, sq);
        sq = fmaf(x.z, x.z, sq); sq = fmaf(x.w, x.w, sq);
        sq = fmaf(y.x, y.x, sq); sq = fmaf(y.y, y.y, sq);
        sq = fmaf(y.z, y.z, sq); sq = fmaf(y.w, y.w, sq);
        u8 o[8] = {to_e4m3(x.x * 64.f), to_e4m3(x.y * 64.f), to_e4m3(x.z * 64.f),
                   to_e4m3(x.w * 64.f), to_e4m3(y.x * 64.f), to_e4m3(y.y * 64.f),
                   to_e4m3(y.z * 64.f), to_e4m3(y.w * 64.f)};
        const int t = k0 >> 6, c = (k0 >> 5) & 1, lp = r15 + ((k0 >> 3) & 3) * 16;
        *(u64*)(Wt + ((size_t)(by * NKT + t) * 16 + rg) * 1024 + lp * 16 + c * 8) =
            *(const u64*)o;
    }
#pragma unroll
    for (int off = 32; off; off >>= 1) sq += __shfl_down(sq, off, 64);
    if (lane == 0) winv[row] = 1.0f / sqrtf(sq);
}

// ---------------- wnorm only (fallback path) ----------------
__global__ __launch_bounds__(256) void wnorm_kernel(const float* __restrict__ W,
                                                    float* __restrict__ winv) {
    int wave = (blockIdx.x * blockDim.x + threadIdx.x) >> 6;
    int lane = threadIdx.x & 63;
    if (wave >= Vv) return;
    const float4* row = (const float4*)(W + (size_t)wave * Dk);
    float s = 0.f;
#pragma unroll
    for (int i = 0; i < Dk / 4 / 64; ++i) {
        float4 v = row[lane + 64 * i];
        s = fmaf(v.x, v.x, s); s = fmaf(v.y, v.y, s);
        s = fmaf(v.z, v.z, s); s = fmaf(v.w, v.w, s);
    }
#pragma unroll
    for (int off = 32; off; off >>= 1) s += __shfl_down(s, off, 64);
    if (lane == 0) winv[wave] = 1.0f / sqrtf(s);
}

__global__ void init_best_kernel(u64* __restrict__ best) {
    int i = blockIdx.x * blockDim.x + threadIdx.x;
    if (i < Mrows) best[i] = 0ull;
}

// ========== Kernel 3 (main): barrier-free fragment-direct fp8 GEMM + top-2 ==========
// Wave (wr 0..1, wc 0..3) computes rows wr*128..+127 x cols wc*64..+63:
// 8 A-frag-pairs + 4 W-frag-pairs per t (12 KB/wave, dwordx4 coalesced),
// 64 MFMA per t. Depth-2 named-register prefetch; no LDS, no barriers in loop.
__global__ __launch_bounds__(512, 2) void score_topk_kernel(
    const u8* __restrict__ At, const u8* __restrict__ Wt,
    const float* __restrict__ winv, u64* __restrict__ cand) {
    __shared__ __align__(16) u64 red[256][8];  // epilogue only (16 KB)

    // XCD-aware bijective swizzle: 1000 = 8 x 125
    const int orig = blockIdx.x;
    const int swz = (orig & 7) * CHUNK + (orig >> 3);
    const int bx = swz & (NBX - 1);
    const int by = swz >> 3;
    const int row0 = bx * BM;
    const int v0 = by * BN;

    const int tid = threadIdx.x;
    const int lane = tid & 63;
    const int w = tid >> 6;   // 0..7
    const int wr = w >> 2;    // 0..1 -> rows wr*128..+127 (rowgrps wr*8..+7)
    const int wc = w & 3;     // 0..3 -> cols wc*64..+63  (colgrps wc*4..+3)

    const u8* pA = At + (size_t)bx * NKT * TSTRIDE + (wr * 8) * 1024 + lane * 16;
    const u8* pW = Wt + (size_t)by * NKT * TSTRIDE + (wc * 4) * 1024 + lane * 16;

    f32x4 acc[8][4];
#pragma unroll
    for (int i = 0; i < 8; ++i)
#pragma unroll
        for (int j = 0; j < 4; ++j) acc[i][j] = (f32x4){0.f, 0.f, 0.f, 0.f};

    i64x2 fa0[8], fw0[4], fa1[8], fw1[4];
    auto LD = [&](int t, i64x2 (&fa)[8], i64x2 (&fw)[4]) {
        const u8* qa = pA + (size_t)t * TSTRIDE;
        const u8* qw = pW + (size_t)t * TSTRIDE;
#pragma unroll
        for (int m = 0; m < 8; ++m) fa[m] = *(const i64x2*)(qa + m * 1024);
#pragma unroll
        for (int n = 0; n < 4; ++n) fw[n] = *(const i64x2*)(qw + n * 1024);
    };
    auto MM = [&](i64x2 (&fa)[8], i64x2 (&fw)[4]) {
#pragma unroll
        for (int c = 0; c < 2; ++c)
#pragma unroll
            for (int m = 0; m < 8; ++m)
#pragma unroll
                for (int n = 0; n < 4; ++n)
                    acc[m][n] = __builtin_amdgcn_mfma_f32_16x16x32_fp8_fp8(
                        fa[m][c], fw[n][c], acc[m][n], 0, 0, 0);
    };

    LD(0, fa0, fw0);
    LD(1, fa1, fw1);
    for (int t = 0; t < NKT; t += 2) {
        MM(fa0, fw0);
        if (t + 2 < NKT) LD(t + 2, fa0, fw0);
        MM(fa1, fw1);
        if (t + 3 < NKT) LD(t + 3, fa1, fw1);
    }

    // ---- epilogue: scale by winv, per-row top-2 within this 256-col block ----
    const int cb = lane & 15;
    float wv[4];
#pragma unroll
    for (int n = 0; n < 4; ++n) wv[n] = winv[v0 + wc * 64 + n * 16 + cb];

#pragma unroll
    for (int m = 0; m < 8; ++m) {
#pragma unroll
        for (int reg = 0; reg < 4; ++reg) {
            u64 b1 = 0, b2 = 0;
#pragma unroll
            for (int n = 0; n < 4; ++n) {
                float s = acc[m][n][reg] * wv[n];
                int v = v0 + wc * 64 + n * 16 + cb;
                u64 p = ((u64)fkey(s) << 32) | (unsigned)(Vv - 1 - v);
                top2(b1, b2, p);
            }
#pragma unroll
            for (int msk = 1; msk < 16; msk <<= 1) {
                u64 o1 = shfl64(b1, msk);
                u64 o2 = shfl64(b2, msk);
                top2(b1, b2, o1);
                top2(b1, b2, o2);
            }
            if (cb == 0) {
                int rl = wr * 128 + m * 16 + ((lane >> 4) << 2) + reg;
                red[rl][wc * 2] = b1;
                red[rl][wc * 2 + 1] = b2;
            }
        }
    }
    __syncthreads();
    if (tid < BM) {
        u64 b1 = red[tid][0], b2 = red[tid][1];
#pragma unroll
        for (int j = 2; j < 8; ++j) top2(b1, b2, red[tid][j]);
        u64* c = cand + (size_t)(row0 + tid) * CAND_STRIDE + by * 2;
        c[0] = b1;
        c[1] = b2;
    }
}

// ------ fallback epilogue (128x128 bf16 path) ------
template <typename LdsT>
__device__ __forceinline__ void topk_epilogue_f(f32x4 (&acc)[4][4], LdsT* ldsbase,
                                                const float* __restrict__ winv,
                                                u64* __restrict__ cand, int row0, int v0,
                                                int vby, int tid, int lane, int wr,
                                                int wc) {
    const int cbase = v0 + wc * 64 + (lane & 15);
    float wv[4];
#pragma unroll
    for (int nf = 0; nf < 4; ++nf) wv[nf] = winv[cbase + nf * 16];

    u64(*red)[4] = (u64(*)[4])ldsbase;
#pragma unroll
    for (int mf = 0; mf < 4; ++mf) {
#pragma unroll
        for (int reg = 0; reg < 4; ++reg) {
            u64 b1 = 0, b2 = 0;
#pragma unroll
            for (int nf = 0; nf < 4; ++nf) {
                float s = acc[mf][nf][reg] * wv[nf];
                int v = cbase + nf * 16;
                u64 p = ((u64)fkey(s) << 32) | (unsigned)(Vv - 1 - v);
                top2(b1, b2, p);
            }
#pragma unroll
            for (int m = 1; m < 16; m <<= 1) {
                u64 o1 = shfl64(b1, m);
                u64 o2 = shfl64(b2, m);
                top2(b1, b2, o1);
                top2(b1, b2, o2);
            }
            if ((lane & 15) == 0) {
                int rl = wr * 64 + mf * 16 + ((lane >> 4) << 2) + reg;
                red[rl][wc * 2] = b1;
                red[rl][wc * 2 + 1] = b2;
            }
        }
    }
    __syncthreads();
    if (tid < FBM) {
        u64 b1 = red[tid][0], b2 = red[tid][1];
        top2(b1, b2, red[tid][2]);
        top2(b1, b2, red[tid][3]);
        u64* c = cand + (size_t)(row0 + tid) * CAND_STRIDE + vby * 2;
        c[0] = b1;
        c[1] = b2;
    }
}

// ---------- Kernel 3 (fallback, small ws): reg-staged f32->bf16 GEMM ----------
__global__ __launch_bounds__(256) void score_topk_fallback(
    const float* __restrict__ A, const float* __restrict__ W,
    const float* __restrict__ winv, u64* __restrict__ cand) {
    __shared__ __align__(16) short Albuf[4096];
    __shared__ __align__(16) short Wlbuf[4096];

    const int tid = threadIdx.x;
    const int row0 = blockIdx.x * FBM;
    const int v0 = blockIdx.y * FBN;
    const int lane = tid & 63;
    const int wid = tid >> 6;
    const int wr = wid >> 1, wc = wid & 1;

    const int rA = ((tid >> 6) << 4) + (tid & 15);
    const int kk = ((tid >> 4) & 3) * 8;

    const float* pa = A + (size_t)(row0 + rA) * Dk + kk;
    const float* pw = W + (size_t)(v0 + rA) * Dk + kk;

    float4 fa0, fa1, fa2, fa3, fw0, fw1, fw2, fw3;
    auto ld4 = [](const float* p) { return *(const float4*)p; };
    auto load_regs = [&](int k0) {
        fa0 = ld4(pa + k0); fa1 = ld4(pa + k0 + 4);
        fa2 = ld4(pa + k0 + (size_t)64 * Dk); fa3 = ld4(pa + k0 + (size_t)64 * Dk + 4);
        fw0 = ld4(pw + k0); fw1 = ld4(pw + k0 + 4);
        fw2 = ld4(pw + k0 + (size_t)64 * Dk); fw3 = ld4(pw + k0 + (size_t)64 * Dk + 4);
    };
    auto pk = [](float lo, float hi) {
        return (int)((__float_as_uint(lo) >> 16) | (__float_as_uint(hi) & 0xFFFF0000u));
    };
    auto cv = [&](float4 a, float4 b) {
        int4 r; r.x = pk(a.x, a.y); r.y = pk(a.z, a.w);
        r.z = pk(b.x, b.y); r.w = pk(b.z, b.w); return r;
    };
    auto write_lds = [&]() {
        *(int4*)(Albuf + tid * 8) = cv(fa0, fa1);
        *(int4*)(Albuf + tid * 8 + 2048) = cv(fa2, fa3);
        *(int4*)(Wlbuf + tid * 8) = cv(fw0, fw1);
        *(int4*)(Wlbuf + tid * 8 + 2048) = cv(fw2, fw3);
    };

    f32x4 acc[4][4];
#pragma unroll
    for (int i = 0; i < 4; ++i)
#pragma unroll
        for (int j = 0; j < 4; ++j) acc[i][j] = (f32x4){0.f, 0.f, 0.f, 0.f};

    load_regs(0);
    for (int kt = 0; kt < Dk / 32; ++kt) {
        write_lds();
        __syncthreads();
        if (kt + 1 < Dk / 32) load_regs((kt + 1) * 32);
        short8v af[4], bf[4];
        const short8v* Ap = (const short8v*)Albuf;
        const short8v* Wp = (const short8v*)Wlbuf;
#pragma unroll
        for (int mf = 0; mf < 4; ++mf) af[mf] = Ap[(wr * 4 + mf) * 64 + lane];
#pragma unroll
        for (int nf = 0; nf < 4; ++nf) bf[nf] = Wp[(wc * 4 + nf) * 64 + lane];
#pragma unroll
        for (int mf = 0; mf < 4; ++mf)
#pragma unroll
            for (int nf = 0; nf < 4; ++nf)
                acc[mf][nf] = __builtin_amdgcn_mfma_f32_16x16x32_bf16(
                    af[mf], bf[nf], acc[mf][nf], 0, 0, 0);
        __syncthreads();
    }

    topk_epilogue_f(acc, Albuf, winv, cand, row0, v0, blockIdx.y, tid, lane, wr, wc);
}

// ---------------- Kernel 4: per-row top-8 of nents candidates ----------------
__global__ __launch_bounds__(256) void topk_kernel(const u64* __restrict__ cand,
                                                   int* __restrict__ sel, int nents) {
    int row = blockIdx.x * 4 + (threadIdx.x >> 6);
    int lane = threadIdx.x & 63;
    if (row >= Mrows) return;
    const u64* c = cand + (size_t)row * CAND_STRIDE;
    u64 v[8];
#pragma unroll
    for (int i = 0; i < 8; ++i) {
        int idx = lane + i * 64;
        v[i] = (idx < nents) ? c[idx] : 0ull;
    }
#pragma unroll
    for (int it = 0; it < KCAND; ++it) {
        u64 lm = 0;
#pragma unroll
        for (int i = 0; i < 8; ++i) lm = v[i] > lm ? v[i] : lm;
#pragma unroll
        for (int m = 32; m; m >>= 1) {
            u64 o = shfl64(lm, m);
            lm = o > lm ? o : lm;
        }
#pragma unroll
        for (int i = 0; i < 8; ++i)
            if (v[i] == lm) v[i] = 0;  // packed values unique -> removes one
        if (lane == 0) sel[row * KCAND + it] = Vv - 1 - (int)(unsigned)(lm & 0xFFFFFFFFu);
    }
}

// ---------------- Kernel 5: exact f32 rescore of top-8 ----------------
__global__ __launch_bounds__(256) void rescore_kernel(
    const float* __restrict__ A, const float* __restrict__ W,
    const float* __restrict__ winv, const int* __restrict__ sel,
    u64* __restrict__ best) {
    int gw = (int)((blockIdx.x * blockDim.x + threadIdx.x) >> 6);
    int lane = threadIdx.x & 63;
    if (gw >= Mrows * KCAND) return;
    int row = gw >> 3, c = gw & 7;
    int v = sel[row * KCAND + c];
    const float4* a = (const float4*)(A + (size_t)row * Dk);
    const float4* w = (const float4*)(W + (size_t)v * Dk);
    float s = 0.f;
#pragma unroll
    for (int i = 0; i < Dk / 4 / 64; ++i) {
        float4 x = a[lane + 64 * i], y = w[lane + 64 * i];
        s = fmaf(x.x, y.x, s); s = fmaf(x.y, y.y, s);
        s = fmaf(x.z, y.z, s); s = fmaf(x.w, y.w, s);
    }
#pragma unroll
    for (int m = 32; m; m >>= 1) s += __shfl_xor(s, m, 64);
    if (lane == 0) {
        u64 p = ((u64)fkey(s * winv[v]) << 32) | (unsigned)(Vv - 1 - v);
        atomicMax(best + row, p);
    }
}

// ---------------- Kernel 6: blend + emit quantize_index ----------------
__global__ __launch_bounds__(256) void blend_kernel(
    const float* __restrict__ emb, const int* __restrict__ ids,
    const u64* __restrict__ best, float* __restrict__ out) {
    int row = blockIdx.x;
    int b = row / Tt;
    int t = row % Tt;
    int idx;
    if (t < Ll) {
        idx = Vv - 1 - (int)(best[b * Ll + t] & 0xFFFFFFFFu);
    } else {
        idx = ids[row];
    }
    const float4* src = (const float4*)(emb + (size_t)idx * Dk);
    float4* dst = (float4*)(out + (size_t)row * Dk);
    for (int i = threadIdx.x; i < Dk / 4; i += blockDim.x) dst[i] = src[i];
    if (t < Ll && threadIdx.x == 0) {
        out[(size_t)Bb * Tt * Dk + (size_t)(b * Ll + t)] = (float)idx;
    }
}

extern "C" void kernel_launch(void* const* d_in, const int* in_sizes, int n_in,
                              void* d_out, int out_size, void* d_ws, size_t ws_size,
                              hipStream_t stream) {
    const float* encoder_outs = (const float*)d_in[0];
    const float* embed_weight = (const float*)d_in[1];
    const int* input_ids = (const int*)d_in[2];

    float* out = (float*)d_out;

    float* winv = (float*)d_ws;
    u64* best = (u64*)((char*)d_ws + 131072);
    int* sel = (int*)((char*)d_ws + 147456);
    u64* cand = (u64*)((char*)d_ws + 262144);
    u8* At = (u8*)((char*)d_ws + 8454144);
    u8* Wt = (u8*)((char*)d_ws + 16842752);

    init_best_kernel<<<(Mrows + 255) / 256, 256, 0, stream>>>(best);

    if (ws_size >= WS_NEEDED) {
        convertA_fp8<<<Mrows / 4, 256, 0, stream>>>(encoder_outs, At);
        convertW_fp8<<<Vv / 4, 256, 0, stream>>>(embed_weight, Wt, winv);
        score_topk_kernel<<<NWG, 512, 0, stream>>>(At, Wt, winv, cand);
        topk_kernel<<<Mrows / 4, 256, 0, stream>>>(cand, sel, 2 * NBY);  // 250
    } else {
        wnorm_kernel<<<Vv * 64 / 256, 256, 0, stream>>>(embed_weight, winv);
        dim3 grid(Mrows / FBM, Vv / FBN);
        score_topk_fallback<<<grid, 256, 0, stream>>>(encoder_outs, embed_weight, winv,
                                                      cand);
        topk_kernel<<<Mrows / 4, 256, 0, stream>>>(cand, sel, 2 * FNVB);  // 500
    }
    rescore_kernel<<<Mrows * KCAND / 4, 256, 0, stream>>>(encoder_outs, embed_weight,
                                                          winv, sel, best);
    blend_kernel<<<Bb * Tt, 256, 0, stream>>>(embed_weight, input_ids, best, out);
}

// Round 14
// 938.108 us; speedup vs baseline: 1.4345x; 1.4345x over previous
//
#include <hip/hip_runtime.h>
#include <hip/hip_fp8.h>
#include <math.h>

typedef __attribute__((ext_vector_type(8))) short short8v;  // 8 bf16
typedef __attribute__((ext_vector_type(4))) float f32x4;
typedef unsigned long long u64;
typedef unsigned short ushort_t;
typedef unsigned char u8;

constexpr int Bb = 4;
constexpr int Ll = 512;
constexpr int Dk = 2048;
constexpr int Vv = 32000;
constexpr int Tt = 1024;
constexpr int Mrows = Bb * Ll;  // 2048

// main GEMM: 128x256 block-tile, 8 waves (2x4 grid, 64x64 wave-tile), fp8 e4m3,
// BK=64/t, WAVE-PRIVATE LDS double-buffers, per-wave counted vmcnt, ZERO block
// barriers in the main loop (fully decoupled wave pipelines).
constexpr int BM = 128;
constexpr int BN = 256;
constexpr int NKT = 32;          // K-tiles of 64
constexpr int NBX = Mrows / BM;  // 16
constexpr int NBY = Vv / BN;     // 125
constexpr int NWG = NBX * NBY;   // 2000 (divisible by 8)
constexpr int CHUNK = NWG / 8;   // 250
// tiled operand granule (same as R12): [blk256][t][rg16][1024]; lane l holds
// 16 B at granule+l*16: row = rg*16+(l&15), k = t*64 + c*32 + (l>>4)*8 + j
// (c = byte 0..7 vs 8..15).
constexpr int TSTRIDE = 16 * 1024;  // bytes per (256-row blk, t)

constexpr int KCAND = 8;          // rescored candidates per row
constexpr int CAND_STRIDE = 500;  // u64 per row; main path uses first 250

// fallback geometry (small-ws path, 128x128 reg-staged bf16)
constexpr int FBM = 128;
constexpr int FBN = 128;
constexpr int FNVB = Vv / FBN;  // 250

// ---- workspace layout (bytes) ----
// winv : f32[32000]         @ 0          (131072 B slot)
// best : u64[2048]          @ 131072     (16384 B)
// sel  : i32[2048*8]        @ 147456     (65536 B)
// cand : u64[2048*500]      @ 262144     (8192000 B)
// At   : fp8 tiled A        @ 8454144    (4194304 B)   [bx8][t32][rg16][1024]
// Wt   : fp8 tiled W        @ 16842752   (65536000 B)  [by125][t32][rg16][1024]
constexpr size_t WS_NEEDED = 16842752ull + 65536000ull;  // 82378752

__device__ __forceinline__ unsigned int fkey(float f) {
    unsigned int u = __float_as_uint(f);
    return (u & 0x80000000u) ? ~u : (u | 0x80000000u);
}
__device__ __forceinline__ void top2(u64& b1, u64& b2, u64 p) {
    if (p > b1) { b2 = b1; b1 = p; }
    else if (p > b2) { b2 = p; }
}
__device__ __forceinline__ u64 shfl64(u64 x, int m) {
    unsigned lo = __shfl_xor((unsigned)x, m, 64);
    unsigned hi = __shfl_xor((unsigned)(x >> 32), m, 64);
    return ((u64)hi << 32) | lo;
}
__device__ __forceinline__ u8 to_e4m3(float x) {
    __hip_fp8_e4m3 q(x);  // OCP e4m3fn, RNE+sat
    return q.__x;
}
// async global->LDS, 16B per lane; global src per-lane, lds dst wave-uniform
__device__ __forceinline__ void gload_lds16(const void* g, void* l) {
    __builtin_amdgcn_global_load_lds(
        (const __attribute__((address_space(1))) unsigned int*)g,
        (__attribute__((address_space(3))) unsigned int*)l, 16, 0, 0);
}

// ---- convert A: f32 -> fp8 e4m3, tiled in 1KB fragment-granules (as R12) ----
__global__ __launch_bounds__(256) void convertA_fp8(const float* __restrict__ A,
                                                    u8* __restrict__ At) {
    const int row = blockIdx.x * 4 + (threadIdx.x >> 6);
    const int lane = threadIdx.x & 63;
    const int bx = row >> 8, rg = (row & 255) >> 4, r15 = row & 15;
    const float* src = A + (size_t)row * Dk;
#pragma unroll
    for (int i = 0; i < 4; ++i) {
        const int k0 = (i * 64 + lane) * 8;
        float4 x = *(const float4*)(src + k0);
        float4 y = *(const float4*)(src + k0 + 4);
        u8 o[8] = {to_e4m3(x.x), to_e4m3(x.y), to_e4m3(x.z), to_e4m3(x.w),
                   to_e4m3(y.x), to_e4m3(y.y), to_e4m3(y.z), to_e4m3(y.w)};
        const int t = k0 >> 6, c = (k0 >> 5) & 1, lp = r15 + ((k0 >> 3) & 3) * 16;
        *(u64*)(At + ((size_t)(bx * NKT + t) * 16 + rg) * 1024 + lp * 16 + c * 8) =
            *(const u64*)o;
    }
}

// ---- convert W: f32 -> fp8 e4m3 (x64 uniform scale), tiled + fused winv ----
__global__ __launch_bounds__(256) void convertW_fp8(const float* __restrict__ W,
                                                    u8* __restrict__ Wt,
                                                    float* __restrict__ winv) {
    const int row = blockIdx.x * 4 + (threadIdx.x >> 6);
    const int lane = threadIdx.x & 63;
    const int by = row >> 8, rg = (row & 255) >> 4, r15 = row & 15;
    const float* src = W + (size_t)row * Dk;
    float sq = 0.f;
#pragma unroll
    for (int i = 0; i < 4; ++i) {
        const int k0 = (i * 64 + lane) * 8;
        float4 x = *(const float4*)(src + k0);
        float4 y = *(const float4*)(src + k0 + 4);
        sq = fmaf(x.x, x.x, sq); sq = fmaf(x.y, x.y, sq);
        sq = fmaf(x.z, x.z, sq); sq = fmaf(x.w, x.w, sq);
        sq = fmaf(y.x, y.x, sq); sq = fmaf(y.y, y.y, sq);
        sq = fmaf(y.z, y.z, sq); sq = fmaf(y.w, y.w, sq);
        u8 o[8] = {to_e4m3(x.x * 64.f), to_e4m3(x.y * 64.f), to_e4m3(x.z * 64.f),
                   to_e4m3(x.w * 64.f), to_e4m3(y.x * 64.f), to_e4m3(y.y * 64.f),
                   to_e4m3(y.z * 64.f), to_e4m3(y.w * 64.f)};
        const int t = k0 >> 6, c = (k0 >> 5) & 1, lp = r15 + ((k0 >> 3) & 3) * 16;
        *(u64*)(Wt + ((size_t)(by * NKT + t) * 16 + rg) * 1024 + lp * 16 + c * 8) =
            *(const u64*)o;
    }
#pragma unroll
    for (int off = 32; off; off >>= 1) sq += __shfl_down(sq, off, 64);
    if (lane == 0) winv[row] = 1.0f / sqrtf(sq);
}

// ---------------- wnorm only (fallback path) ----------------
__global__ __launch_bounds__(256) void wnorm_kernel(const float* __restrict__ W,
                                                    float* __restrict__ winv) {
    int wave = (blockIdx.x * blockDim.x + threadIdx.x) >> 6;
    int lane = threadIdx.x & 63;
    if (wave >= Vv) return;
    const float4* row = (const float4*)(W + (size_t)wave * Dk);
    float s = 0.f;
#pragma unroll
    for (int i = 0; i < Dk / 4 / 64; ++i) {
        float4 v = row[lane + 64 * i];
        s = fmaf(v.x, v.x, s); s = fmaf(v.y, v.y, s);
        s = fmaf(v.z, v.z, s); s = fmaf(v.w, v.w, s);
    }
#pragma unroll
    for (int off = 32; off; off >>= 1) s += __shfl_down(s, off, 64);
    if (lane == 0) winv[wave] = 1.0f / sqrtf(s);
}

__global__ void init_best_kernel(u64* __restrict__ best) {
    int i = blockIdx.x * blockDim.x + threadIdx.x;
    if (i < Mrows) best[i] = 0ull;
}

// ========== Kernel 3 (main): wave-decoupled fp8 GEMM + per-block top-2 ==========
// Wave w = (wr 0..1, wc 0..3): rows bx*128 + wr*64..+63, cols by*256 + wc*64..+63.
// Private LDS: Abuf[w][2][4KB], Wbuf[w][2][4KB]. Per t: wait vmcnt(8) (own loads
// only), 16 ds_read_b64, 32 MFMA, lgkmcnt(0), stage(t+2). No block barriers.
__global__ __launch_bounds__(512, 2) void score_topk_kernel(
    const u8* __restrict__ At, const u8* __restrict__ Wt,
    const float* __restrict__ winv, u64* __restrict__ cand) {
    __shared__ __align__(16) u8 Abuf[8][2][4096];  // 64 KB
    __shared__ __align__(16) u8 Wbuf[8][2][4096];  // 64 KB
    __shared__ __align__(16) u64 red[BM][8];       // 8 KB (epilogue)

    // XCD-aware bijective swizzle: 2000 = 8 x 250
    const int orig = blockIdx.x;
    const int swz = (orig & 7) * CHUNK + (orig >> 3);
    const int bx = swz & (NBX - 1);   // 0..15
    const int by = swz >> 4;          // 0..124
    const int row0 = bx * BM;
    const int v0 = by * BN;

    const int tid = threadIdx.x;
    const int lane = tid & 63;
    const int w = tid >> 6;   // 0..7
    const int wr = w >> 2;    // 0..1
    const int wc = w & 3;     // 0..3

    // A: block bx covers rg range (bx&1)*8..+7 of At-block bx>>1; wave adds wr*4
    const int rgA = (bx & 1) * 8 + wr * 4;
    const u8* pA = At + (size_t)(bx >> 1) * NKT * TSTRIDE + rgA * 1024 + lane * 16;
    const u8* pW = Wt + (size_t)by * NKT * TSTRIDE + (wc * 4) * 1024 + lane * 16;

    auto stage = [&](int buf, int t) {
        const size_t o = (size_t)t * TSTRIDE;
#pragma unroll
        for (int q = 0; q < 4; ++q)
            gload_lds16(pA + o + q * 1024, &Abuf[w][buf][q * 1024]);
#pragma unroll
        for (int q = 0; q < 4; ++q)
            gload_lds16(pW + o + q * 1024, &Wbuf[w][buf][q * 1024]);
    };

    f32x4 acc[4][4];
#pragma unroll
    for (int i = 0; i < 4; ++i)
#pragma unroll
        for (int j = 0; j < 4; ++j) acc[i][j] = (f32x4){0.f, 0.f, 0.f, 0.f};

    stage(0, 0);
    stage(1, 1);
    for (int t = 0; t < NKT; ++t) {
        // wait for THIS wave's tile-t loads (8 of them); keep t+1's in flight
        if (t + 1 < NKT) asm volatile("s_waitcnt vmcnt(8)" ::: "memory");
        else             asm volatile("s_waitcnt vmcnt(0)" ::: "memory");
        __builtin_amdgcn_sched_barrier(0);
        const u8* Ab = &Abuf[w][t & 1][0];
        const u8* Wb = &Wbuf[w][t & 1][0];
        __builtin_amdgcn_s_setprio(1);
#pragma unroll
        for (int c = 0; c < 2; ++c) {
            long long a[4], b[4];
#pragma unroll
            for (int m = 0; m < 4; ++m)
                a[m] = *(const long long*)(Ab + m * 1024 + lane * 16 + c * 8);
#pragma unroll
            for (int n = 0; n < 4; ++n)
                b[n] = *(const long long*)(Wb + n * 1024 + lane * 16 + c * 8);
#pragma unroll
            for (int m = 0; m < 4; ++m)
#pragma unroll
                for (int n = 0; n < 4; ++n)
                    acc[m][n] = __builtin_amdgcn_mfma_f32_16x16x32_fp8_fp8(
                        a[m], b[n], acc[m][n], 0, 0, 0);
        }
        __builtin_amdgcn_s_setprio(0);
        __builtin_amdgcn_sched_barrier(0);
        // architectural guard: all my ds_reads retired before overwriting buffer
        asm volatile("s_waitcnt lgkmcnt(0)" ::: "memory");
        __builtin_amdgcn_sched_barrier(0);
        if (t + 2 < NKT) stage(t & 1, t + 2);
    }

    // ---- epilogue: scale by winv, per-row top-2 within this 256-col block ----
    const int cb = lane & 15;
    float wv[4];
#pragma unroll
    for (int n = 0; n < 4; ++n) wv[n] = winv[v0 + wc * 64 + n * 16 + cb];

#pragma unroll
    for (int m = 0; m < 4; ++m) {
#pragma unroll
        for (int reg = 0; reg < 4; ++reg) {
            u64 b1 = 0, b2 = 0;
#pragma unroll
            for (int n = 0; n < 4; ++n) {
                float s = acc[m][n][reg] * wv[n];
                int v = v0 + wc * 64 + n * 16 + cb;
                u64 p = ((u64)fkey(s) << 32) | (unsigned)(Vv - 1 - v);
                top2(b1, b2, p);
            }
#pragma unroll
            for (int msk = 1; msk < 16; msk <<= 1) {
                u64 o1 = shfl64(b1, msk);
                u64 o2 = shfl64(b2, msk);
                top2(b1, b2, o1);
                top2(b1, b2, o2);
            }
            if (cb == 0) {
                int rl = wr * 64 + m * 16 + ((lane >> 4) << 2) + reg;
                red[rl][wc * 2] = b1;
                red[rl][wc * 2 + 1] = b2;
            }
        }
    }
    __syncthreads();
    if (tid < BM) {
        u64 b1 = red[tid][0], b2 = red[tid][1];
#pragma unroll
        for (int j = 2; j < 8; ++j) top2(b1, b2, red[tid][j]);
        u64* c = cand + (size_t)(row0 + tid) * CAND_STRIDE + by * 2;
        c[0] = b1;
        c[1] = b2;
    }
}

// ------ fallback epilogue (128x128 bf16 path) ------
template <typename LdsT>
__device__ __forceinline__ void topk_epilogue_f(f32x4 (&acc)[4][4], LdsT* ldsbase,
                                                const float* __restrict__ winv,
                                                u64* __restrict__ cand, int row0, int v0,
                                                int vby, int tid, int lane, int wr,
                                                int wc) {
    const int cbase = v0 + wc * 64 + (lane & 15);
    float wv[4];
#pragma unroll
    for (int nf = 0; nf < 4; ++nf) wv[nf] = winv[cbase + nf * 16];

    u64(*red)[4] = (u64(*)[4])ldsbase;
#pragma unroll
    for (int mf = 0; mf < 4; ++mf) {
#pragma unroll
        for (int reg = 0; reg < 4; ++reg) {
            u64 b1 = 0, b2 = 0;
#pragma unroll
            for (int nf = 0; nf < 4; ++nf) {
                float s = acc[mf][nf][reg] * wv[nf];
                int v = cbase + nf * 16;
                u64 p = ((u64)fkey(s) << 32) | (unsigned)(Vv - 1 - v);
                top2(b1, b2, p);
            }
#pragma unroll
            for (int m = 1; m < 16; m <<= 1) {
                u64 o1 = shfl64(b1, m);
                u64 o2 = shfl64(b2, m);
                top2(b1, b2, o1);
                top2(b1, b2, o2);
            }
            if ((lane & 15) == 0) {
                int rl = wr * 64 + mf * 16 + ((lane >> 4) << 2) + reg;
                red[rl][wc * 2] = b1;
                red[rl][wc * 2 + 1] = b2;
            }
        }
    }
    __syncthreads();
    if (tid < FBM) {
        u64 b1 = red[tid][0], b2 = red[tid][1];
        top2(b1, b2, red[tid][2]);
        top2(b1, b2, red[tid][3]);
        u64* c = cand + (size_t)(row0 + tid) * CAND_STRIDE + vby * 2;
        c[0] = b1;
        c[1] = b2;
    }
}

// ---------- Kernel 3 (fallback, small ws): reg-staged f32->bf16 GEMM ----------
__global__ __launch_bounds__(256) void score_topk_fallback(
    const float* __restrict__ A, const float* __restrict__ W,
    const float* __restrict__ winv, u64* __restrict__ cand) {
    __shared__ __align__(16) short Albuf[4096];
    __shared__ __align__(16) short Wlbuf[4096];

    const int tid = threadIdx.x;
    const int row0 = blockIdx.x * FBM;
    const int v0 = blockIdx.y * FBN;
    const int lane = tid & 63;
    const int wid = tid >> 6;
    const int wr = wid >> 1, wc = wid & 1;

    const int rA = ((tid >> 6) << 4) + (tid & 15);
    const int kk = ((tid >> 4) & 3) * 8;

    const float* pa = A + (size_t)(row0 + rA) * Dk + kk;
    const float* pw = W + (size_t)(v0 + rA) * Dk + kk;

    float4 fa0, fa1, fa2, fa3, fw0, fw1, fw2, fw3;
    auto ld4 = [](const float* p) { return *(const float4*)p; };
    auto load_regs = [&](int k0) {
        fa0 = ld4(pa + k0); fa1 = ld4(pa + k0 + 4);
        fa2 = ld4(pa + k0 + (size_t)64 * Dk); fa3 = ld4(pa + k0 + (size_t)64 * Dk + 4);
        fw0 = ld4(pw + k0); fw1 = ld4(pw + k0 + 4);
        fw2 = ld4(pw + k0 + (size_t)64 * Dk); fw3 = ld4(pw + k0 + (size_t)64 * Dk + 4);
    };
    auto pk = [](float lo, float hi) {
        return (int)((__float_as_uint(lo) >> 16) | (__float_as_uint(hi) & 0xFFFF0000u));
    };
    auto cv = [&](float4 a, float4 b) {
        int4 r; r.x = pk(a.x, a.y); r.y = pk(a.z, a.w);
        r.z = pk(b.x, b.y); r.w = pk(b.z, b.w); return r;
    };
    auto write_lds = [&]() {
        *(int4*)(Albuf + tid * 8) = cv(fa0, fa1);
        *(int4*)(Albuf + tid * 8 + 2048) = cv(fa2, fa3);
        *(int4*)(Wlbuf + tid * 8) = cv(fw0, fw1);
        *(int4*)(Wlbuf + tid * 8 + 2048) = cv(fw2, fw3);
    };

    f32x4 acc[4][4];
#pragma unroll
    for (int i = 0; i < 4; ++i)
#pragma unroll
        for (int j = 0; j < 4; ++j) acc[i][j] = (f32x4){0.f, 0.f, 0.f, 0.f};

    load_regs(0);
    for (int kt = 0; kt < Dk / 32; ++kt) {
        write_lds();
        __syncthreads();
        if (kt + 1 < Dk / 32) load_regs((kt + 1) * 32);
        short8v af[4], bf[4];
        const short8v* Ap = (const short8v*)Albuf;
        const short8v* Wp = (const short8v*)Wlbuf;
#pragma unroll
        for (int mf = 0; mf < 4; ++mf) af[mf] = Ap[(wr * 4 + mf) * 64 + lane];
#pragma unroll
        for (int nf = 0; nf < 4; ++nf) bf[nf] = Wp[(wc * 4 + nf) * 64 + lane];
#pragma unroll
        for (int mf = 0; mf < 4; ++mf)
#pragma unroll
            for (int nf = 0; nf < 4; ++nf)
                acc[mf][nf] = __builtin_amdgcn_mfma_f32_16x16x32_bf16(
                    af[mf], bf[nf], acc[mf][nf], 0, 0, 0);
        __syncthreads();
    }

    topk_epilogue_f(acc, Albuf, winv, cand, row0, v0, blockIdx.y, tid, lane, wr, wc);
}

// ---------------- Kernel 4: per-row top-8 of nents candidates ----------------
__global__ __launch_bounds__(256) void topk_kernel(const u64* __restrict__ cand,
                                                   int* __restrict__ sel, int nents) {
    int row = blockIdx.x * 4 + (threadIdx.x >> 6);
    int lane = threadIdx.x & 63;
    if (row >= Mrows) return;
    const u64* c = cand + (size_t)row * CAND_STRIDE;
    u64 v[8];
#pragma unroll
    for (int i = 0; i < 8; ++i) {
        int idx = lane + i * 64;
        v[i] = (idx < nents) ? c[idx] : 0ull;
    }
#pragma unroll
    for (int it = 0; it < KCAND; ++it) {
        u64 lm = 0;
#pragma unroll
        for (int i = 0; i < 8; ++i) lm = v[i] > lm ? v[i] : lm;
#pragma unroll
        for (int m = 32; m; m >>= 1) {
            u64 o = shfl64(lm, m);
            lm = o > lm ? o : lm;
        }
#pragma unroll
        for (int i = 0; i < 8; ++i)
            if (v[i] == lm) v[i] = 0;  // packed values unique -> removes one
        if (lane == 0) sel[row * KCAND + it] = Vv - 1 - (int)(unsigned)(lm & 0xFFFFFFFFu);
    }
}

// ---------------- Kernel 5: exact f32 rescore of top-8 ----------------
__global__ __launch_bounds__(256) void rescore_kernel(
    const float* __restrict__ A, const float* __restrict__ W,
    const float* __restrict__ winv, const int* __restrict__ sel,
    u64* __restrict__ best) {
    int gw = (int)((blockIdx.x * blockDim.x + threadIdx.x) >> 6);
    int lane = threadIdx.x & 63;
    if (gw >= Mrows * KCAND) return;
    int row = gw >> 3, c = gw & 7;
    int v = sel[row * KCAND + c];
    const float4* a = (const float4*)(A + (size_t)row * Dk);
    const float4* w = (const float4*)(W + (size_t)v * Dk);
    float s = 0.f;
#pragma unroll
    for (int i = 0; i < Dk / 4 / 64; ++i) {
        float4 x = a[lane + 64 * i], y = w[lane + 64 * i];
        s = fmaf(x.x, y.x, s); s = fmaf(x.y, y.y, s);
        s = fmaf(x.z, y.z, s); s = fmaf(x.w, y.w, s);
    }
#pragma unroll
    for (int m = 32; m; m >>= 1) s += __shfl_xor(s, m, 64);
    if (lane == 0) {
        u64 p = ((u64)fkey(s * winv[v]) << 32) | (unsigned)(Vv - 1 - v);
        atomicMax(best + row, p);
    }
}

// ---------------- Kernel 6: blend + emit quantize_index ----------------
__global__ __launch_bounds__(256) void blend_kernel(
    const float* __restrict__ emb, const int* __restrict__ ids,
    const u64* __restrict__ best, float* __restrict__ out) {
    int row = blockIdx.x;
    int b = row / Tt;
    int t = row % Tt;
    int idx;
    if (t < Ll) {
        idx = Vv - 1 - (int)(best[b * Ll + t] & 0xFFFFFFFFu);
    } else {
        idx = ids[row];
    }
    const float4* src = (const float4*)(emb + (size_t)idx * Dk);
    float4* dst = (float4*)(out + (size_t)row * Dk);
    for (int i = threadIdx.x; i < Dk / 4; i += blockDim.x) dst[i] = src[i];
    if (t < Ll && threadIdx.x == 0) {
        out[(size_t)Bb * Tt * Dk + (size_t)(b * Ll + t)] = (float)idx;
    }
}

extern "C" void kernel_launch(void* const* d_in, const int* in_sizes, int n_in,
                              void* d_out, int out_size, void* d_ws, size_t ws_size,
                              hipStream_t stream) {
    const float* encoder_outs = (const float*)d_in[0];
    const float* embed_weight = (const float*)d_in[1];
    const int* input_ids = (const int*)d_in[2];

    float* out = (float*)d_out;

    float* winv = (float*)d_ws;
    u64* best = (u64*)((char*)d_ws + 131072);
    int* sel = (int*)((char*)d_ws + 147456);
    u64* cand = (u64*)((char*)d_ws + 262144);
    u8* At = (u8*)((char*)d_ws + 8454144);
    u8* Wt = (u8*)((char*)d_ws + 16842752);

    init_best_kernel<<<(Mrows + 255) / 256, 256, 0, stream>>>(best);

    if (ws_size >= WS_NEEDED) {
        convertA_fp8<<<Mrows / 4, 256, 0, stream>>>(encoder_outs, At);
        convertW_fp8<<<Vv / 4, 256, 0, stream>>>(embed_weight, Wt, winv);
        score_topk_kernel<<<NWG, 512, 0, stream>>>(At, Wt, winv, cand);
        topk_kernel<<<Mrows / 4, 256, 0, stream>>>(cand, sel, 2 * NBY);  // 250
    } else {
        wnorm_kernel<<<Vv * 64 / 256, 256, 0, stream>>>(embed_weight, winv);
        dim3 grid(Mrows / FBM, Vv / FBN);
        score_topk_fallback<<<grid, 256, 0, stream>>>(encoder_outs, embed_weight, winv,
                                                      cand);
        topk_kernel<<<Mrows / 4, 256, 0, stream>>>(cand, sel, 2 * FNVB);  // 500
    }
    rescore_kernel<<<Mrows * KCAND / 4, 256, 0, stream>>>(encoder_outs, embed_weight,
                                                          winv, sel, best);
    blend_kernel<<<Bb * Tt, 256, 0, stream>>>(embed_weight, input_ids, best, out);
}